// Round 6
// baseline (201.200 us; speedup 1.0000x reference)
//
#include <hip/hip_runtime.h>
#include <hip/hip_bf16.h>

typedef __bf16 bf16_t;
typedef bf16_t bf16x8 __attribute__((ext_vector_type(8)));
typedef float  f32x4  __attribute__((ext_vector_type(4)));
typedef float  f32x16 __attribute__((ext_vector_type(16)));
typedef int    i32x4  __attribute__((ext_vector_type(4)));

#define DH 64

// pack two floats into one u32 of 2 bf16 (RNE via cast)
__device__ __forceinline__ unsigned pkbf(float a, float b) {
    union { bf16_t h[2]; unsigned u; } z;
    z.h[0] = (bf16_t)a; z.h[1] = (bf16_t)b;
    return z.u;
}

#if defined(__has_builtin)
#  if __has_builtin(__builtin_amdgcn_exp2f)
#    define EXP2F(x) __builtin_amdgcn_exp2f(x)
#  else
#    define EXP2F(x) exp2f(x)
#  endif
#else
#  define EXP2F(x) exp2f(x)
#endif

// MFMA layout facts (HW-verified, guide m74/m101; kernel-verified R4/R5):
//   32x32 C/D: col = lane&31, row = (reg&3) + 8*(reg>>2) + 4*(lane>>5)
//   A: row = lane&31; B: col = lane&31; k-slot = (lane>>5)*8 + j.
//
// R6: K-split across wave-halves. Waves 0-3 = lower key-half, waves 4-7 =
// upper key-half of the same 4x 32-row subtiles; stripe p has 2(p+1) tiles so
// both halves run exactly p+1 lockstep iterations; stripe-pair (p,15-p) makes
// every block/wave do 17 iterations (uniform). Halves merge via LDS at stripe
// end. Softmax in exp2 domain (log2e folded into Q scale).

__global__ __launch_bounds__(512, 4)
void sdpa_fwd(const float* __restrict__ Qg, const float* __restrict__ Kg,
              const float* __restrict__ Vg, float* __restrict__ Og)
{
    __shared__ char lds[65536];   // stream s buf b: s*32768 + b*16384 (K 8KB | V 8KB)

    const int n  = blockIdx.x;
    const int o  = ((n & 7) << 6) | (n >> 3);   // XCD-chunked swizzle (512%8==0)
    const int bh = o >> 3;                      // 0..63
    const int pr = o & 7;                       // stripe-pair id

    const int t    = threadIdx.x;
    const int w    = t >> 6;                    // wave 0..7
    const int strm = w >> 2;                    // 0 = lower half, 1 = upper half
    const int w4   = w & 3;                     // subtile within stripe
    const int l63  = t & 63;
    const int l31  = t & 31;
    const int hi   = (t >> 5) & 1;
    const int swk  = (l31 & 7) << 4;            // kbuf read swizzle

    const size_t hoff = (size_t)bh * 2048 * DH;
    const float* Qh = Qg + hoff;
    const float* Kh = Kg + hoff;
    const float* Vh = Vg + hoff;
    float*       Oh = Og + hoff;

    // staging map within stream (256 threads -> 64 rows, 2 rows/thread)
    const int st   = t & 255;
    const int srow = (st >> 3) * 2;
    const int sdc  = st & 7;

    const int stripes[2] = { 15 - pr, pr };
    const int iters[2]   = { 16 - pr, pr + 1 };   // h = p+1; total 17

    // T14 prefetch regs: rk/rv [0..1]=row srow, [2..3]=row srow+1
    f32x4 rk[4], rv[4];
    {
        const int kt0 = strm * iters[0];          // first staged tile of stream
        const float* kp = Kh + (size_t)(kt0 * 64 + srow) * DH + sdc * 8;
        rk[0] = *(const f32x4*)kp;        rk[1] = *(const f32x4*)(kp + 4);
        rk[2] = *(const f32x4*)(kp + DH); rk[3] = *(const f32x4*)(kp + DH + 4);
        const float* vp = Vh + (size_t)(kt0 * 64 + srow) * DH + sdc * 8;
        rv[0] = *(const f32x4*)vp;        rv[1] = *(const f32x4*)(vp + 4);
        rv[2] = *(const f32x4*)(vp + DH); rv[3] = *(const f32x4*)(vp + DH + 4);
    }

    float* cb = (float*)lds;        // combine area (reuses stream buffers)
    const float QSCALE = 0.125f * 1.44269504088896f;   // 1/sqrt(64) * log2(e)

    int gi = 0;                     // global iteration counter (buffer parity)
    for (int s = 0; s < 2; ++s) {
        const int p    = stripes[s];
        const int h    = iters[s];              // iterations this stripe
        const int qsb  = p * 128 + w4 * 32;     // wave's 32-row subtile base
        const int qrow = qsb + l31;
        const int ktd  = qsb >> 6;              // diagonal (masked) tile index

        // ---- Q fragments (B operand), pre-scaled (exp2 domain) ----
        bf16x8 qf[4];
#pragma unroll
        for (int sd = 0; sd < 4; ++sd) {
            const float* qp = Qh + (size_t)qrow * DH + sd * 16 + hi * 8;
            f32x4 a = *(const f32x4*)qp;
            f32x4 b = *(const f32x4*)(qp + 4);
            bf16x8 f;
            f[0] = (bf16_t)(a[0]*QSCALE); f[1] = (bf16_t)(a[1]*QSCALE);
            f[2] = (bf16_t)(a[2]*QSCALE); f[3] = (bf16_t)(a[3]*QSCALE);
            f[4] = (bf16_t)(b[0]*QSCALE); f[5] = (bf16_t)(b[1]*QSCALE);
            f[6] = (bf16_t)(b[2]*QSCALE); f[7] = (bf16_t)(b[3]*QSCALE);
            qf[sd] = f;
        }

        f32x16 acc0 = {}, acc1 = {};            // O^T fragments: d 0-31, 32-63
        float m_run = -1e30f, l_run = 0.0f;     // log2-domain running stats

        for (int i = 0; i < h; ++i, ++gi) {
            char* kb_ = lds + strm * 32768 + (gi & 1) * 16384;
            char* vb_ = kb_ + 8192;

            // ---- stage prefetched tile into this stream's buf ----
            {
#pragma unroll
                for (int r2 = 0; r2 < 2; ++r2) {
                    const int key = srow + r2;
                    bf16x8 f;
                    f[0] = (bf16_t)rk[r2*2][0];   f[1] = (bf16_t)rk[r2*2][1];
                    f[2] = (bf16_t)rk[r2*2][2];   f[3] = (bf16_t)rk[r2*2][3];
                    f[4] = (bf16_t)rk[r2*2+1][0]; f[5] = (bf16_t)rk[r2*2+1][1];
                    f[6] = (bf16_t)rk[r2*2+1][2]; f[7] = (bf16_t)rk[r2*2+1][3];
                    *(bf16x8*)(kb_ + ((key * 128 + sdc * 16) ^ ((key & 7) << 4))) = f;
                }
#pragma unroll
                for (int jj = 0; jj < 8; ++jj) {   // V transpose, b32 pair writes
                    const int d  = sdc * 8 + jj;
                    const float x0 = (jj < 4) ? rv[0][jj & 3] : rv[1][jj & 3];
                    const float x1 = (jj < 4) ? rv[2][jj & 3] : rv[3][jj & 3];
                    *(unsigned*)(vb_ + ((d * 128 + srow * 2) ^ (((jj ^ sdc) & 7) << 4)))
                        = pkbf(x0, x1);
                }
            }
            // ---- prefetch next staged tile (block-uniform control) ----
            {
                int ni = i + 1, ns = s;
                if (ni >= h) { ns = s + 1; ni = 0; }
                if (ns < 2) {
                    const int nk = strm * iters[ns] + ni;
                    const float* kp = Kh + (size_t)(nk * 64 + srow) * DH + sdc * 8;
                    rk[0] = *(const f32x4*)kp;        rk[1] = *(const f32x4*)(kp + 4);
                    rk[2] = *(const f32x4*)(kp + DH); rk[3] = *(const f32x4*)(kp + DH + 4);
                    const float* vp = Vh + (size_t)(nk * 64 + srow) * DH + sdc * 8;
                    rv[0] = *(const f32x4*)vp;        rv[1] = *(const f32x4*)(vp + 4);
                    rv[2] = *(const f32x4*)(vp + DH); rv[3] = *(const f32x4*)(vp + DH + 4);
                }
            }
            __syncthreads();   // stream buffers ready (dbuf => 1 barrier/iter safe)

            const int ktc = strm * h + i;        // tile this wave computes
            if (ktc <= ktd) {
                // ---- QK^T: lane holds q = l31; key blocks {l31, 32+l31} ----
                f32x16 tf0 = {}, tf1 = {};
#pragma unroll
                for (int sd = 0; sd < 4; ++sd) {
                    const int inner = sd * 32 + hi * 16;
                    const bf16x8 k0 = *(const bf16x8*)(kb_ + ((l31 * 128 + inner) ^ swk));
                    const bf16x8 k1 = *(const bf16x8*)(kb_ + (((32 + l31) * 128 + inner) ^ swk));
                    tf0 = __builtin_amdgcn_mfma_f32_32x32x16_bf16(k0, qf[sd], tf0, 0, 0, 0);
                    tf1 = __builtin_amdgcn_mfma_f32_32x32x16_bf16(k1, qf[sd], tf1, 0, 0, 0);
                }

                if (ktc == ktd) {   // only the diagonal tile needs masking
#pragma unroll
                    for (int r = 0; r < 16; ++r) {
                        const int krow = ktc * 64 + (r & 3) + 8 * (r >> 2) + 4 * hi;
                        if (krow > qrow)      tf0[r] = -20000.0f;
                        if (krow + 32 > qrow) tf1[r] = -20000.0f;
                    }
                }

                // ---- online softmax, exp2 domain ----
                float mx = tf0[0];
#pragma unroll
                for (int r = 1; r < 16; ++r) mx = fmaxf(mx, tf0[r]);
#pragma unroll
                for (int r = 0; r < 16; ++r) mx = fmaxf(mx, tf1[r]);
                mx = fmaxf(mx, __shfl_xor(mx, 32));

                if (!__all(mx <= m_run + 11.0f)) {     // T13 defer-max (log2 units)
                    const float mnew  = fmaxf(m_run, mx);
                    const float alpha = EXP2F(m_run - mnew);
                    m_run = mnew;
                    l_run *= alpha;
                    acc0 *= alpha;
                    acc1 *= alpha;
                }

                float sum = 0.0f;
#pragma unroll
                for (int r = 0; r < 16; ++r) { tf0[r] = EXP2F(tf0[r] - m_run); sum += tf0[r]; }
#pragma unroll
                for (int r = 0; r < 16; ++r) { tf1[r] = EXP2F(tf1[r] - m_run); sum += tf1[r]; }
                sum += __shfl_xor(sum, 32);
                l_run += sum;

                // ---- pack P to bf16 pairs ----
                unsigned P0[2][4], P1[2][4];
#pragma unroll
                for (int rg = 0; rg < 4; ++rg) {
                    P0[0][rg] = pkbf(tf0[rg * 4 + 0], tf0[rg * 4 + 1]);
                    P1[0][rg] = pkbf(tf0[rg * 4 + 2], tf0[rg * 4 + 3]);
                    P0[1][rg] = pkbf(tf1[rg * 4 + 0], tf1[rg * 4 + 1]);
                    P1[1][rg] = pkbf(tf1[rg * 4 + 2], tf1[rg * 4 + 3]);
                }

                // ---- PV: O^T += V^T · P^T (in-register P redistribution) ----
#pragma unroll
                for (int sidx = 0; sidx < 4; ++sidx) {
                    const int kb  = sidx >> 1;
                    const int rgl = (sidx & 1) * 2, rgh = rgl + 1;
                    int w0, w1, w2, w3;
#if defined(__has_builtin) && __has_builtin(__builtin_amdgcn_permlane32_swap)
                    auto r0 = __builtin_amdgcn_permlane32_swap((int)P0[kb][rgl], (int)P0[kb][rgh], false, false);
                    auto r1 = __builtin_amdgcn_permlane32_swap((int)P1[kb][rgl], (int)P1[kb][rgh], false, false);
                    w0 = r0[0]; w2 = r0[1]; w1 = r1[0]; w3 = r1[1];
#else
                    const int sa0 = __shfl_xor((int)P0[kb][rgl], 32);
                    const int sb0 = __shfl_xor((int)P0[kb][rgh], 32);
                    const int sa1 = __shfl_xor((int)P1[kb][rgl], 32);
                    const int sb1 = __shfl_xor((int)P1[kb][rgh], 32);
                    w0 = hi ? sb0 : (int)P0[kb][rgl];
                    w2 = hi ? (int)P0[kb][rgh] : sa0;
                    w1 = hi ? sb1 : (int)P1[kb][rgl];
                    w3 = hi ? (int)P1[kb][rgh] : sa1;
#endif
                    union { i32x4 ii; bf16x8 v; } pz;
                    pz.ii = (i32x4){ w0, w1, w2, w3 };

                    const int inner = sidx * 32 + hi * 16;
                    const int d0 = l31;
                    const int d1 = 32 + l31;
                    const int sz0 = (((d0 & 7) ^ (d0 >> 3)) & 7) << 4;
                    const int sz1 = (((d1 & 7) ^ (d1 >> 3)) & 7) << 4;
                    const bf16x8 v0 = *(const bf16x8*)(vb_ + ((d0 * 128 + inner) ^ sz0));
                    const bf16x8 v1 = *(const bf16x8*)(vb_ + ((d1 * 128 + inner) ^ sz1));
                    acc0 = __builtin_amdgcn_mfma_f32_32x32x16_bf16(v0, pz.v, acc0, 0, 0, 0);
                    acc1 = __builtin_amdgcn_mfma_f32_32x32x16_bf16(v1, pz.v, acc1, 0, 0, 0);
                }
            }
        }

        // ---- merge halves via LDS (stride 35 f32: lane stride 35%32=3, CF) ----
        __syncthreads();                 // all compute done; buffers reusable
        const int cbase = (w4 * 64 + l63) * 35;
        if (strm == 1) {
#pragma unroll
            for (int r = 0; r < 16; ++r) { cb[cbase + r] = acc0[r]; cb[cbase + 16 + r] = acc1[r]; }
            cb[cbase + 32] = m_run;
            cb[cbase + 33] = l_run;
        }
        __syncthreads();
        if (strm == 0) {
            const float m_b = cb[cbase + 32];
            const float l_b = cb[cbase + 33];
            const float mst = fmaxf(m_run, m_b);
            const float aa  = EXP2F(m_run - mst);
            const float ab  = EXP2F(m_b  - mst);
            const float inv = 1.0f / (l_run * aa + l_b * ab);

            float* op = Oh + (size_t)qrow * DH;
#pragma unroll
            for (int rq = 0; rq < 4; ++rq) {
                f32x4 o0, o1;
#pragma unroll
                for (int j = 0; j < 4; ++j) {
                    o0[j] = (acc0[rq*4+j] * aa + cb[cbase + rq*4 + j]      * ab) * inv;
                    o1[j] = (acc1[rq*4+j] * aa + cb[cbase + 16 + rq*4 + j] * ab) * inv;
                }
                *(f32x4*)(op + 8 * rq + 4 * hi)      = o0;
                *(f32x4*)(op + 32 + 8 * rq + 4 * hi) = o1;
            }
        }
        __syncthreads();                 // protect LDS before next stripe staging
    }
}

extern "C" void kernel_launch(void* const* d_in, const int* in_sizes, int n_in,
                              void* d_out, int out_size, void* d_ws, size_t ws_size,
                              hipStream_t stream) {
    (void)in_sizes; (void)n_in; (void)d_ws; (void)ws_size; (void)out_size;
    const float* q = (const float*)d_in[0];
    const float* k = (const float*)d_in[1];
    const float* v = (const float*)d_in[2];
    // d_in[3] (tril mask) applied analytically — identical semantics.
    float* out = (float*)d_out;
    hipLaunchKernelGGL(sdpa_fwd, dim3(512), dim3(512), 0, stream, q, k, v, out);
}

// Round 7
// 73.889 us; speedup vs baseline: 2.7230x; 2.7230x over previous
//
#include <hip/hip_runtime.h>
#include <hip/hip_bf16.h>

typedef __bf16 bf16_t;
typedef bf16_t bf16x8 __attribute__((ext_vector_type(8)));
typedef float  f32x4  __attribute__((ext_vector_type(4)));
typedef float  f32x16 __attribute__((ext_vector_type(16)));
typedef int    i32x4  __attribute__((ext_vector_type(4)));

#define DH 64

// pack two floats into one u32 of 2 bf16 (RNE via cast)
__device__ __forceinline__ unsigned pkbf(float a, float b) {
    union { bf16_t h[2]; unsigned u; } z;
    z.h[0] = (bf16_t)a; z.h[1] = (bf16_t)b;
    return z.u;
}

#if defined(__has_builtin)
#  if __has_builtin(__builtin_amdgcn_exp2f)
#    define EXP2F(x) __builtin_amdgcn_exp2f(x)
#  else
#    define EXP2F(x) exp2f(x)
#  endif
#else
#  define EXP2F(x) exp2f(x)
#endif

// MFMA layout facts (HW-verified, guide m74/m101; kernel-verified R4/R5/R6):
//   32x32 C/D: col = lane&31, row = (reg&3) + 8*(reg>>2) + 4*(lane>>5)
//   A: row = lane&31; B: col = lane&31; k-slot = (lane>>5)*8 + j.
//
// R7 = R5 structure (stripe-pair balance, 512x256, 8 XCD-partner blocks/head
// on one XCD -> L2-shared K/V prefixes) + software pipeline: compute tile gt
// from buf[gt&1] WHILE staging gt+1 into the other buf; global prefetch runs
// one full iteration ahead (tile gt+2). One barrier per iter, at iter end.
// exp2-domain softmax (log2e folded into Q scale). setprio around MFMA.

__global__ __launch_bounds__(256, 2)
void sdpa_fwd(const float* __restrict__ Qg, const float* __restrict__ Kg,
              const float* __restrict__ Vg, float* __restrict__ Og)
{
    __shared__ char lds[2 * 16384];   // buf b: b*16384 (K-img 8KB | V-img 8KB)

    const int n  = blockIdx.x;
    const int o  = ((n & 7) << 6) | (n >> 3);   // XCD-chunked swizzle (512%8==0)
    const int bh = o >> 3;                      // 0..63
    const int pr = o & 7;                       // stripe-pair id

    const int t   = threadIdx.x;
    const int w   = t >> 6;                     // wave 0..3
    const int l31 = t & 31;
    const int hi  = (t >> 5) & 1;
    const int swk = (l31 & 7) << 4;             // kbuf read swizzle

    const size_t hoff = (size_t)bh * 2048 * DH;
    const float* Qh = Qg + hoff;
    const float* Kh = Kg + hoff;
    const float* Vh = Vg + hoff;
    float*       Oh = Og + hoff;

    // staging map: thread -> key rows {srow, srow+1}, d-chunk sdc*8..sdc*8+7
    const int srow = (t >> 3) * 2;
    const int sdc  = t & 7;

    const int p0  = 15 - pr;           // heavy stripe first
    const int nk0 = 2 * p0 + 2;        // its tile count
    const int NT  = 34;                // total staged tiles (uniform all blocks)

    f32x4 rk[4], rv[4];                // prefetch regs

    auto loadKV = [&](int key0) {
        const float* kp = Kh + (size_t)(key0 + srow) * DH + sdc * 8;
        rk[0] = *(const f32x4*)kp;        rk[1] = *(const f32x4*)(kp + 4);
        rk[2] = *(const f32x4*)(kp + DH); rk[3] = *(const f32x4*)(kp + DH + 4);
        const float* vp = Vh + (size_t)(key0 + srow) * DH + sdc * 8;
        rv[0] = *(const f32x4*)vp;        rv[1] = *(const f32x4*)(vp + 4);
        rv[2] = *(const f32x4*)(vp + DH); rv[3] = *(const f32x4*)(vp + DH + 4);
    };
    auto stageTo = [&](char* kb_, char* vb_) {
#pragma unroll
        for (int r2 = 0; r2 < 2; ++r2) {
            const int key = srow + r2;
            bf16x8 f;
            f[0] = (bf16_t)rk[r2*2][0];   f[1] = (bf16_t)rk[r2*2][1];
            f[2] = (bf16_t)rk[r2*2][2];   f[3] = (bf16_t)rk[r2*2][3];
            f[4] = (bf16_t)rk[r2*2+1][0]; f[5] = (bf16_t)rk[r2*2+1][1];
            f[6] = (bf16_t)rk[r2*2+1][2]; f[7] = (bf16_t)rk[r2*2+1][3];
            *(bf16x8*)(kb_ + ((key * 128 + sdc * 16) ^ ((key & 7) << 4))) = f;
        }
#pragma unroll
        for (int jj = 0; jj < 8; ++jj) {    // V transpose, b32 pair writes
            const int d  = sdc * 8 + jj;
            const float x0 = (jj < 4) ? rv[0][jj & 3] : rv[1][jj & 3];
            const float x1 = (jj < 4) ? rv[2][jj & 3] : rv[3][jj & 3];
            *(unsigned*)(vb_ + ((d * 128 + srow * 2) ^ (((jj ^ sdc) & 7) << 4)))
                = pkbf(x0, x1);
        }
    };
    auto keybase = [&](int g) { return ((g < nk0) ? g : g - nk0) * 64; };

    const float QSCALE = 0.125f * 1.44269504088896f;   // 1/sqrt(64) * log2(e)

    // ---- pipeline prologue: tile0 staged; tile1 in regs ----
    loadKV(0);
    stageTo(lds, lds + 8192);
    loadKV(keybase(1));
    __syncthreads();

    int gt = 0;
    const int stripes[2] = { p0, pr };
    for (int s = 0; s < 2; ++s) {
        const int p    = stripes[s];
        const int h    = 2 * p + 2;
        const int qsb  = p * 128 + w * 32;    // wave's 32-row subtile base
        const int qrow = qsb + l31;
        const int ktd  = qsb >> 6;            // diagonal (masked) tile index

        // ---- Q fragments (B operand), pre-scaled (exp2 domain) ----
        bf16x8 qf[4];
#pragma unroll
        for (int sd = 0; sd < 4; ++sd) {
            const float* qp = Qh + (size_t)qrow * DH + sd * 16 + hi * 8;
            f32x4 a = *(const f32x4*)qp;
            f32x4 b = *(const f32x4*)(qp + 4);
            bf16x8 f;
            f[0] = (bf16_t)(a[0]*QSCALE); f[1] = (bf16_t)(a[1]*QSCALE);
            f[2] = (bf16_t)(a[2]*QSCALE); f[3] = (bf16_t)(a[3]*QSCALE);
            f[4] = (bf16_t)(b[0]*QSCALE); f[5] = (bf16_t)(b[1]*QSCALE);
            f[6] = (bf16_t)(b[2]*QSCALE); f[7] = (bf16_t)(b[3]*QSCALE);
            qf[sd] = f;
        }

        f32x16 acc0 = {}, acc1 = {};          // O^T fragments: d 0-31, 32-63
        float m_run = -1e30f, l_run = 0.0f;   // log2-domain running stats

        for (int i = 0; i < h; ++i, ++gt) {
            char* cb_ = lds + (gt & 1) * 16384;         // compute buf (tile gt)
            char* sb_ = lds + ((gt + 1) & 1) * 16384;   // stage buf (tile gt+1)

            // stage next tile from regs; then refill regs one tile further out
            if (gt + 1 < NT) stageTo(sb_, sb_ + 8192);
            if (gt + 2 < NT) loadKV(keybase(gt + 2));

            if (i <= ktd) {
                char* kb_ = cb_;
                char* vb_ = cb_ + 8192;

                // ---- QK^T: lane holds q = l31; key blocks {l31, 32+l31} ----
                f32x16 tf0 = {}, tf1 = {};
                __builtin_amdgcn_s_setprio(1);
#pragma unroll
                for (int sd = 0; sd < 4; ++sd) {
                    const int inner = sd * 32 + hi * 16;
                    const bf16x8 k0 = *(const bf16x8*)(kb_ + ((l31 * 128 + inner) ^ swk));
                    const bf16x8 k1 = *(const bf16x8*)(kb_ + (((32 + l31) * 128 + inner) ^ swk));
                    tf0 = __builtin_amdgcn_mfma_f32_32x32x16_bf16(k0, qf[sd], tf0, 0, 0, 0);
                    tf1 = __builtin_amdgcn_mfma_f32_32x32x16_bf16(k1, qf[sd], tf1, 0, 0, 0);
                }
                __builtin_amdgcn_s_setprio(0);

                if (i == ktd) {   // only the diagonal tile needs masking
#pragma unroll
                    for (int r = 0; r < 16; ++r) {
                        const int krow = i * 64 + (r & 3) + 8 * (r >> 2) + 4 * hi;
                        if (krow > qrow)      tf0[r] = -20000.0f;
                        if (krow + 32 > qrow) tf1[r] = -20000.0f;
                    }
                }

                // ---- online softmax, exp2 domain ----
                float mx = tf0[0];
#pragma unroll
                for (int r = 1; r < 16; ++r) mx = fmaxf(mx, tf0[r]);
#pragma unroll
                for (int r = 0; r < 16; ++r) mx = fmaxf(mx, tf1[r]);
                mx = fmaxf(mx, __shfl_xor(mx, 32));

                if (!__all(mx <= m_run + 11.0f)) {     // T13 defer-max (log2 units)
                    const float mnew  = fmaxf(m_run, mx);
                    const float alpha = EXP2F(m_run - mnew);
                    m_run = mnew;
                    l_run *= alpha;
                    acc0 *= alpha;
                    acc1 *= alpha;
                }

                float sum = 0.0f;
#pragma unroll
                for (int r = 0; r < 16; ++r) { tf0[r] = EXP2F(tf0[r] - m_run); sum += tf0[r]; }
#pragma unroll
                for (int r = 0; r < 16; ++r) { tf1[r] = EXP2F(tf1[r] - m_run); sum += tf1[r]; }
                sum += __shfl_xor(sum, 32);
                l_run += sum;

                // ---- pack P to bf16 pairs ----
                unsigned P0[2][4], P1[2][4];
#pragma unroll
                for (int rg = 0; rg < 4; ++rg) {
                    P0[0][rg] = pkbf(tf0[rg * 4 + 0], tf0[rg * 4 + 1]);
                    P1[0][rg] = pkbf(tf0[rg * 4 + 2], tf0[rg * 4 + 3]);
                    P0[1][rg] = pkbf(tf1[rg * 4 + 0], tf1[rg * 4 + 1]);
                    P1[1][rg] = pkbf(tf1[rg * 4 + 2], tf1[rg * 4 + 3]);
                }

                // ---- PV: O^T += V^T · P^T (in-register P redistribution) ----
                __builtin_amdgcn_s_setprio(1);
#pragma unroll
                for (int sidx = 0; sidx < 4; ++sidx) {
                    const int kb  = sidx >> 1;
                    const int rgl = (sidx & 1) * 2, rgh = rgl + 1;
                    int w0, w1, w2, w3;
#if defined(__has_builtin) && __has_builtin(__builtin_amdgcn_permlane32_swap)
                    auto r0 = __builtin_amdgcn_permlane32_swap((int)P0[kb][rgl], (int)P0[kb][rgh], false, false);
                    auto r1 = __builtin_amdgcn_permlane32_swap((int)P1[kb][rgl], (int)P1[kb][rgh], false, false);
                    w0 = r0[0]; w2 = r0[1]; w1 = r1[0]; w3 = r1[1];
#else
                    const int sa0 = __shfl_xor((int)P0[kb][rgl], 32);
                    const int sb0 = __shfl_xor((int)P0[kb][rgh], 32);
                    const int sa1 = __shfl_xor((int)P1[kb][rgl], 32);
                    const int sb1 = __shfl_xor((int)P1[kb][rgh], 32);
                    w0 = hi ? sb0 : (int)P0[kb][rgl];
                    w2 = hi ? (int)P0[kb][rgh] : sa0;
                    w1 = hi ? sb1 : (int)P1[kb][rgl];
                    w3 = hi ? (int)P1[kb][rgh] : sa1;
#endif
                    union { i32x4 ii; bf16x8 v; } pz;
                    pz.ii = (i32x4){ w0, w1, w2, w3 };

                    const int inner = sidx * 32 + hi * 16;
                    const int d0 = l31;
                    const int d1 = 32 + l31;
                    const int sz0 = (((d0 & 7) ^ (d0 >> 3)) & 7) << 4;
                    const int sz1 = (((d1 & 7) ^ (d1 >> 3)) & 7) << 4;
                    const bf16x8 v0 = *(const bf16x8*)(vb_ + ((d0 * 128 + inner) ^ sz0));
                    const bf16x8 v1 = *(const bf16x8*)(vb_ + ((d1 * 128 + inner) ^ sz1));
                    acc0 = __builtin_amdgcn_mfma_f32_32x32x16_bf16(v0, pz.v, acc0, 0, 0, 0);
                    acc1 = __builtin_amdgcn_mfma_f32_32x32x16_bf16(v1, pz.v, acc1, 0, 0, 0);
                }
                __builtin_amdgcn_s_setprio(0);
            }
            __syncthreads();    // staging of gt+1 done; all reads of buf gt done
        }

        // ---- stripe epilogue: O[q][d] = acc^T / l (global only, no LDS) ----
        const float inv = 1.0f / l_run;
        float* op = Oh + (size_t)qrow * DH;
#pragma unroll
        for (int rq = 0; rq < 4; ++rq) {
            f32x4 o0, o1;
#pragma unroll
            for (int j = 0; j < 4; ++j) {
                o0[j] = acc0[rq * 4 + j] * inv;
                o1[j] = acc1[rq * 4 + j] * inv;
            }
            *(f32x4*)(op + 8 * rq + 4 * hi)      = o0;
            *(f32x4*)(op + 32 + 8 * rq + 4 * hi) = o1;
        }
    }
}

extern "C" void kernel_launch(void* const* d_in, const int* in_sizes, int n_in,
                              void* d_out, int out_size, void* d_ws, size_t ws_size,
                              hipStream_t stream) {
    (void)in_sizes; (void)n_in; (void)d_ws; (void)ws_size; (void)out_size;
    const float* q = (const float*)d_in[0];
    const float* k = (const float*)d_in[1];
    const float* v = (const float*)d_in[2];
    // d_in[3] (tril mask) applied analytically — identical semantics.
    float* out = (float*)d_out;
    hipLaunchKernelGGL(sdpa_fwd, dim3(512), dim3(256), 0, stream, q, k, v, out);
}